// Round 17
// baseline (120.118 us; speedup 1.0000x reference)
//
#include <hip/hip_runtime.h>
#include <math.h>

// Quantum circuit simulator: BATCH=2048 states x 1024 complex amplitudes,
// QDEPTH=8 layers of StronglyEntanglingLayers (10 Rot gates + 10 CNOTs).
//
// Round-17 = r13 math (validated best, 48.6us) x TWO INDEPENDENT STATES PER
// WAVE (1024 blocks). Distinct from the thrice-falsified state-SPLIT axis
// (r10/r12/r15 split one state across waves -> +VALU work each time): the
// merge adds zero work -- total VALU cycles, DS ops, conflicts unchanged;
// coefficient scalar loads halve (shared). Gain: state B's FMA chain is
// independent of state A's bpermute/LDS-read waits -> ILP overlap inside
// one wave, instead of relying on the 2-wave/SIMD scheduler (measured to
// leave VALU at 46% and DS at 41%, wall ~= serial sum).
// Per-state structure byte-identical to r13:
//  - packs over t: zr[k]=(re[t=k],re[t=k+8]) -> element-wise v_pk_fma_f32.
//  - wires 9..7: cross-pack register gates; wire 6: in-pack half-swap.
//  - wires 5..2: DPP row ops (VALU); wires 1,0: __shfl_xor (DS bpermute).
//  - CNOT: composed GF(2)-linear permutation, one LDS round trip, t-major
//    b32 word(i)=t*64+lane (the only conflict-free layout: 1.3e5), XOR
//    tables in d_ws; B's LDS region at +1024 (same bank pattern).
// No __syncthreads (single wave per block; per-wave DS ops in-order).

#define WIRES   10
#define NSTATE  1024
#define QDEPTH  8
#define NBATCH  2048
#define NGATES  (QDEPTH * WIRES)

typedef float v2f __attribute__((ext_vector_type(2)));
static __device__ __forceinline__ v2f s2(float x) { return (v2f){x, x}; }

// ws layout (floats/ints, 4 B each)  [identical to r13 -- validated]:
//   [0   .. 640)  gate coeffs gi=(l*10+q): u00r,u00i,u01r,u01i,u10r,u10i,u11r,u11i
//   [640 .. 768)  int gt[l*16+t]    = word(g_l(t))
//   [768 .. 1280) int glane[l*64+v] = word(g_l(v<<4))
#define WS_WORDS 1280

__device__ __forceinline__ int perm_g(int j, int r) {
#pragma unroll
    for (int q = WIRES - 1; q >= 0; --q) {
        const int cb = 9 - q;
        const int tb = 9 - ((q + r) % WIRES);
        j ^= ((j >> cb) & 1) << tb;
    }
    return j;
}

__global__ __launch_bounds__(1024) void qprep(
    const float* __restrict__ weights, float* __restrict__ ws)
{
    const int tid = threadIdx.x;
    if (tid < NGATES) {
        const float phi   = tanhf(weights[tid * 3 + 0]);
        const float theta = tanhf(weights[tid * 3 + 1]);
        const float omega = tanhf(weights[tid * 3 + 2]);
        const float c  = cosf(theta * 0.5f);
        const float sn = sinf(theta * 0.5f);
        const float a  = 0.5f * (phi + omega);
        const float bb = 0.5f * (phi - omega);
        const float ca = cosf(a),  sa = sinf(a);
        const float cb = cosf(bb), sb = sinf(bb);
        // U00 = e^{-ia} c ; U01 = -e^{+ib} s ; U10 = e^{-ib} s ; U11 = e^{+ia} c
        ws[tid * 8 + 0] =  ca * c;  ws[tid * 8 + 1] = -sa * c;
        ws[tid * 8 + 2] = -cb * sn; ws[tid * 8 + 3] = -sb * sn;
        ws[tid * 8 + 4] =  cb * sn; ws[tid * 8 + 5] = -sb * sn;
        ws[tid * 8 + 6] =  ca * c;  ws[tid * 8 + 7] =  sa * c;
    }
    int* wsI = (int*)ws;
    if (tid >= 128 && tid < 256) {          // gt table: 8 layers x 16 t
        const int e = tid - 128, l = e >> 4, t = e & 15;
        const int j = perm_g(t, (l % (WIRES - 1)) + 1);
        wsI[640 + e] = ((j & 15) << 6) | (j >> 4);
    }
    if (tid >= 256 && tid < 768) {          // glane table: 8 layers x 64 lanes
        const int e = tid - 256, l = e >> 6, v = e & 63;
        const int j = perm_g(v << 4, (l % (WIRES - 1)) + 1);
        wsI[768 + e] = ((j & 15) << 6) | (j >> 4);
    }
}

// DPP cross-lane move (VALU pipe, rows of 16 lanes) — validated r9/r13
template<int CTRL>
__device__ __forceinline__ float dppmov(float x) {
    return __int_as_float(__builtin_amdgcn_update_dpp(
        0, __float_as_int(x), CTRL, 0xF, 0xF, true));
}
#define FX1(v)  dppmov<0xB1>(v)
#define FX2(v)  dppmov<0x4E>(v)
#define FX4(v)  dppmov<0x1B>(dppmov<0x141>(v))
#define FX8(v)  dppmov<0x128>(v)
#define FX16(v) __shfl_xor((v), 16, 64)
#define FX32(v) __shfl_xor((v), 32, 64)

// local 2x2 gate along t-bit mask (1,2,4) on state (ZR,ZI)
#define APPLY_LOCAL_PK(ZR, ZI, uptr, mask)                                    \
    {                                                                         \
        const float* __restrict__ u = (uptr);                                 \
        const float u00r=u[0], u00i=u[1], u01r=u[2], u01i=u[3];               \
        const float u10r=u[4], u10i=u[5], u11r=u[6], u11i=u[7];               \
        _Pragma("unroll")                                                     \
        for (int k0 = 0; k0 < 8; ++k0) {                                      \
            if (k0 & (mask)) continue;                                        \
            const int k1 = k0 | (mask);                                       \
            const v2f a0r = ZR[k0], a0i = ZI[k0];                             \
            const v2f a1r = ZR[k1], a1i = ZI[k1];                             \
            ZR[k0] = s2(u00r)*a0r - s2(u00i)*a0i + s2(u01r)*a1r - s2(u01i)*a1i;\
            ZI[k0] = s2(u00r)*a0i + s2(u00i)*a0r + s2(u01r)*a1i + s2(u01i)*a1r;\
            ZR[k1] = s2(u10r)*a0r - s2(u10i)*a0i + s2(u11r)*a1r - s2(u11i)*a1i;\
            ZI[k1] = s2(u10r)*a0i + s2(u10i)*a0r + s2(u11r)*a1i + s2(u11i)*a1r;\
        }                                                                     \
    }

// wire-6 (pack-dim) gate: lo<->hi half-swap with packed constants
#define HALF_SWAP_PK(ZR, ZI, uptr)                                            \
    {                                                                         \
        const float* __restrict__ u = (uptr);                                 \
        const v2f pAr = (v2f){u[0], u[6]};                                    \
        const v2f pAi = (v2f){u[1], u[7]};                                    \
        const v2f pBr = (v2f){u[2], u[4]};                                    \
        const v2f pBi = (v2f){u[3], u[5]};                                    \
        _Pragma("unroll")                                                     \
        for (int k = 0; k < 8; ++k) {                                         \
            const v2f r  = ZR[k], i = ZI[k];                                  \
            const v2f rs = __builtin_shufflevector(r, r, 1, 0);               \
            const v2f is = __builtin_shufflevector(i, i, 1, 0);               \
            ZR[k] = pAr*r - pAi*i + pBr*rs - pBi*is;                          \
            ZI[k] = pAr*i + pAi*r + pBr*is + pBi*rs;                          \
        }                                                                     \
    }

// gate on lane-bit J (wire W) on state (ZR,ZI), partner via FETCH
#define LANE_GATE_PK(ZR, ZI, W, J, FETCH)                                     \
    {                                                                         \
        const float* __restrict__ u = gw + (W) * 8;                           \
        const bool hi = (lane >> (J)) & 1;                                    \
        const float c0r = hi ? u[6] : u[0], c0i = hi ? u[7] : u[1];           \
        const float c1r = hi ? u[4] : u[2], c1i = hi ? u[5] : u[3];           \
        _Pragma("unroll")                                                     \
        for (int k = 0; k < 8; ++k) {                                         \
            v2f pr, pi;                                                       \
            pr.x = FETCH(ZR[k].x); pr.y = FETCH(ZR[k].y);                     \
            pi.x = FETCH(ZI[k].x); pi.y = FETCH(ZI[k].y);                     \
            const v2f sr = ZR[k], si = ZI[k];                                 \
            ZR[k] = s2(c0r)*sr - s2(c0i)*si + s2(c1r)*pr - s2(c1i)*pi;        \
            ZI[k] = s2(c0r)*si + s2(c0i)*sr + s2(c1r)*pi + s2(c1i)*pr;        \
        }                                                                     \
    }

__global__ __launch_bounds__(64) void qsim_2s(
    const float* __restrict__ x,
    const float* __restrict__ ws,
    float* __restrict__ out,
    const int interleaved)
{
    // A planes at [0,1024), B planes at [1024,2048) — same bank pattern
    __shared__ float lre[2 * NSTATE];
    __shared__ float lim[2 * NSTATE];
    const int lane = threadIdx.x;           // 0..63
    const int b    = blockIdx.x;            // 0..1023: states 2b, 2b+1
    const int* __restrict__ wsI = (const int*)ws;

    v2f zrA[8], ziA[8], zrB[8], ziB[8];

    // ---- load 16 contiguous amplitudes per state (real input, imag 0) ----
    {
        const float4* __restrict__ xA =
            (const float4*)(x + ((size_t)(2 * b) << 10) + (lane << 4));
        const float4* __restrict__ xB =
            (const float4*)(x + ((size_t)(2 * b + 1) << 10) + (lane << 4));
        const float4 a0 = xA[0], a1 = xA[1], a2 = xA[2], a3 = xA[3];
        const float4 b0 = xB[0], b1 = xB[1], b2 = xB[2], b3 = xB[3];
        zrA[0].x=a0.x; zrA[1].x=a0.y; zrA[2].x=a0.z; zrA[3].x=a0.w;
        zrA[4].x=a1.x; zrA[5].x=a1.y; zrA[6].x=a1.z; zrA[7].x=a1.w;
        zrA[0].y=a2.x; zrA[1].y=a2.y; zrA[2].y=a2.z; zrA[3].y=a2.w;
        zrA[4].y=a3.x; zrA[5].y=a3.y; zrA[6].y=a3.z; zrA[7].y=a3.w;
        zrB[0].x=b0.x; zrB[1].x=b0.y; zrB[2].x=b0.z; zrB[3].x=b0.w;
        zrB[4].x=b1.x; zrB[5].x=b1.y; zrB[6].x=b1.z; zrB[7].x=b1.w;
        zrB[0].y=b2.x; zrB[1].y=b2.y; zrB[2].y=b2.z; zrB[3].y=b2.w;
        zrB[4].y=b3.x; zrB[5].y=b3.y; zrB[6].y=b3.z; zrB[7].y=b3.w;
#pragma unroll
        for (int k = 0; k < 8; ++k) {
            ziA[k] = (v2f){0.f, 0.f};
            ziB[k] = (v2f){0.f, 0.f};
        }
    }

    for (int l = 0; l < QDEPTH; ++l) {
        const float* __restrict__ gw = ws + l * 80;

        // ---- local gates (VALU only), A/B interleaved for ILP ----
        APPLY_LOCAL_PK(zrA, ziA, gw + 9*8, 1)
        APPLY_LOCAL_PK(zrB, ziB, gw + 9*8, 1)
        APPLY_LOCAL_PK(zrA, ziA, gw + 8*8, 2)
        APPLY_LOCAL_PK(zrB, ziB, gw + 8*8, 2)
        APPLY_LOCAL_PK(zrA, ziA, gw + 7*8, 4)
        APPLY_LOCAL_PK(zrB, ziB, gw + 7*8, 4)
        HALF_SWAP_PK(zrA, ziA, gw + 6*8)
        HALF_SWAP_PK(zrB, ziB, gw + 6*8)

        // ---- lane-bit gates: wires 5..2 DPP (VALU), wires 1,0 bpermute ----
        LANE_GATE_PK(zrA, ziA, 5, 0, FX1)
        LANE_GATE_PK(zrB, ziB, 5, 0, FX1)
        LANE_GATE_PK(zrA, ziA, 4, 1, FX2)
        LANE_GATE_PK(zrB, ziB, 4, 1, FX2)
        LANE_GATE_PK(zrA, ziA, 3, 2, FX4)
        LANE_GATE_PK(zrB, ziB, 3, 2, FX4)
        LANE_GATE_PK(zrA, ziA, 2, 3, FX8)
        LANE_GATE_PK(zrB, ziB, 2, 3, FX8)
        // B's DS fetches issue behind A's; B's FMA overlaps A's lgkm waits
        LANE_GATE_PK(zrA, ziA, 1, 4, FX16)
        LANE_GATE_PK(zrB, ziB, 1, 4, FX16)
        LANE_GATE_PK(zrA, ziA, 0, 5, FX32)
        LANE_GATE_PK(zrB, ziB, 0, 5, FX32)

        // ---- CNOT stage: one LDS round trip per state, B region at +1024 ----
#pragma unroll
        for (int k = 0; k < 8; ++k) {
            lre[k * 64 + lane]       = zrA[k].x;
            lre[(k + 8) * 64 + lane] = zrA[k].y;
            lim[k * 64 + lane]       = ziA[k].x;
            lim[(k + 8) * 64 + lane] = ziA[k].y;
        }
#pragma unroll
        for (int k = 0; k < 8; ++k) {
            lre[1024 + k * 64 + lane]       = zrB[k].x;
            lre[1024 + (k + 8) * 64 + lane] = zrB[k].y;
            lim[1024 + k * 64 + lane]       = ziB[k].x;
            lim[1024 + (k + 8) * 64 + lane] = ziB[k].y;
        }
        // single wave: per-wave DS ops execute in order; no barrier needed
        const int ga = wsI[768 + l * 64 + lane];    // word(g(lane<<4))
#pragma unroll
        for (int k = 0; k < 8; ++k) {
            const int a0 = ga ^ wsI[640 + l * 16 + k];
            const int a1 = ga ^ wsI[640 + l * 16 + k + 8];
            zrA[k].x = lre[a0];        ziA[k].x = lim[a0];
            zrA[k].y = lre[a1];        ziA[k].y = lim[a1];
            zrB[k].x = lre[1024 + a0]; ziB[k].x = lim[1024 + a0];
            zrB[k].y = lre[1024 + a1]; ziB[k].y = lim[1024 + a1];
        }
    }

    // ---- epilogue ----
    if (interleaved) {
        float2* __restrict__ o2 = (float2*)out;
        const size_t baseA = ((size_t)(2 * b) << 10) + (lane << 4);
        const size_t baseB = ((size_t)(2 * b + 1) << 10) + (lane << 4);
#pragma unroll
        for (int k = 0; k < 8; ++k) {
            o2[baseA + k]     = make_float2(zrA[k].x, ziA[k].x);
            o2[baseA + k + 8] = make_float2(zrA[k].y, ziA[k].y);
            o2[baseB + k]     = make_float2(zrB[k].x, ziB[k].x);
            o2[baseB + k + 8] = make_float2(zrB[k].y, ziB[k].y);
        }
    } else {
        // harness compares real part only (complex64 expected cast to f32)
        float4* __restrict__ oA = (float4*)(out + ((size_t)(2 * b) << 10) + (lane << 4));
        float4* __restrict__ oB = (float4*)(out + ((size_t)(2 * b + 1) << 10) + (lane << 4));
        oA[0] = make_float4(zrA[0].x, zrA[1].x, zrA[2].x, zrA[3].x);
        oA[1] = make_float4(zrA[4].x, zrA[5].x, zrA[6].x, zrA[7].x);
        oA[2] = make_float4(zrA[0].y, zrA[1].y, zrA[2].y, zrA[3].y);
        oA[3] = make_float4(zrA[4].y, zrA[5].y, zrA[6].y, zrA[7].y);
        oB[0] = make_float4(zrB[0].x, zrB[1].x, zrB[2].x, zrB[3].x);
        oB[1] = make_float4(zrB[4].x, zrB[5].x, zrB[6].x, zrB[7].x);
        oB[2] = make_float4(zrB[0].y, zrB[1].y, zrB[2].y, zrB[3].y);
        oB[3] = make_float4(zrB[4].y, zrB[5].y, zrB[6].y, zrB[7].y);
    }
}

// ---------------- validated round-6 fallback (ws too small) ----------------
__global__ __launch_bounds__(256) void qcircuit_kernel(
    const float* __restrict__ x, const float* __restrict__ weights,
    float* __restrict__ out, const int interleaved)
{
    __shared__ float s_re[NSTATE];
    __shared__ float s_im[NSTATE];
    __shared__ float s_g[NGATES][8];
    const int tid = threadIdx.x;
    const int b   = blockIdx.x;
    if (tid < NGATES) {
        const float phi   = tanhf(weights[tid * 3 + 0]);
        const float theta = tanhf(weights[tid * 3 + 1]);
        const float omega = tanhf(weights[tid * 3 + 2]);
        const float c  = cosf(theta * 0.5f);
        const float sn = sinf(theta * 0.5f);
        const float a  = 0.5f * (phi + omega);
        const float bb = 0.5f * (phi - omega);
        const float ca = cosf(a),  sa = sinf(a);
        const float cb = cosf(bb), sb = sinf(bb);
        s_g[tid][0] =  ca * c;  s_g[tid][1] = -sa * c;
        s_g[tid][2] = -cb * sn; s_g[tid][3] = -sb * sn;
        s_g[tid][4] =  cb * sn; s_g[tid][5] = -sb * sn;
        s_g[tid][6] =  ca * c;  s_g[tid][7] =  sa * c;
    }
#pragma unroll
    for (int k = 0; k < 4; ++k) {
        const int i = tid + 256 * k;
        s_re[i] = x[b * NSTATE + i];
        s_im[i] = 0.0f;
    }
    __syncthreads();
    for (int l = 0; l < QDEPTH; ++l) {
        for (int q = 0; q < WIRES; ++q) {
            const int gi = l * WIRES + q;
            const float u00r = s_g[gi][0], u00i = s_g[gi][1];
            const float u01r = s_g[gi][2], u01i = s_g[gi][3];
            const float u10r = s_g[gi][4], u10i = s_g[gi][5];
            const float u11r = s_g[gi][6], u11i = s_g[gi][7];
            const int sh = 9 - q;
            const int m  = 1 << sh;
#pragma unroll
            for (int k = 0; k < 2; ++k) {
                const int p  = tid + 256 * k;
                const int i0 = ((p >> sh) << (sh + 1)) | (p & (m - 1));
                const int i1 = i0 | m;
                const float a0r = s_re[i0], a0i = s_im[i0];
                const float a1r = s_re[i1], a1i = s_im[i1];
                s_re[i0] = u00r*a0r - u00i*a0i + u01r*a1r - u01i*a1i;
                s_im[i0] = u00r*a0i + u00i*a0r + u01r*a1i + u01i*a1r;
                s_re[i1] = u10r*a0r - u10i*a0i + u11r*a1r - u11i*a1i;
                s_im[i1] = u10r*a0i + u10i*a0r + u11r*a1i + u11i*a1r;
            }
            __syncthreads();
        }
        const int r = (l % (WIRES - 1)) + 1;
        float vr[4], vi[4];
#pragma unroll
        for (int k = 0; k < 4; ++k) {
            const int i = tid + 256 * k;
            const int j = perm_g(i, r);
            vr[k] = s_re[j]; vi[k] = s_im[j];
        }
        __syncthreads();
#pragma unroll
        for (int k = 0; k < 4; ++k) {
            const int i = tid + 256 * k;
            s_re[i] = vr[k]; s_im[i] = vi[k];
        }
        __syncthreads();
    }
    if (interleaved) {
#pragma unroll
        for (int k = 0; k < 4; ++k) {
            const int i  = tid + 256 * k;
            const int fi = 2 * (b * NSTATE + i);
            out[fi + 0] = s_re[i];
            out[fi + 1] = s_im[i];
        }
    } else {
#pragma unroll
        for (int k = 0; k < 4; ++k) {
            const int i = tid + 256 * k;
            out[b * NSTATE + i] = s_re[i];
        }
    }
}

extern "C" void kernel_launch(void* const* d_in, const int* in_sizes, int n_in,
                              void* d_out, int out_size, void* d_ws, size_t ws_size,
                              hipStream_t stream) {
    const float* x       = (const float*)d_in[0];   // (2048,1,32,32) f32
    const float* weights = (const float*)d_in[1];   // (8,10,3) f32
    float* out = (float*)d_out;
    const int interleaved = (out_size >= 2 * NBATCH * NSTATE) ? 1 : 0;

    if (ws_size >= WS_WORDS * sizeof(float)) {
        float* ws = (float*)d_ws;
        qprep<<<1, 1024, 0, stream>>>(weights, ws);
        qsim_2s<<<NBATCH / 2, 64, 0, stream>>>(x, ws, out, interleaved);
    } else {
        qcircuit_kernel<<<NBATCH, 256, 0, stream>>>(x, weights, out, interleaved);
    }
}

// Round 18
// 104.135 us; speedup vs baseline: 1.1535x; 1.1535x over previous
//
#include <hip/hip_runtime.h>
#include <math.h>

// Quantum circuit simulator: BATCH=2048 states x 1024 complex amplitudes,
// QDEPTH=8 layers of StronglyEntanglingLayers (10 Rot gates + 10 CNOTs).
//
// FINAL (= round-13/16, validated best: kernel 48.6-49.9us, harness ~104us).
// Session map (kernel-only times):
//   r6 LDS/256thr 96us -> r7 wave/state+shfl 66us -> r9 +DPP 53.5us
//   -> r13 +t-dim packing (v_pk_fma) 48.6us   [this kernel]
// Topology space fully mapped (measured, explained):
//   - SPLIT state across waves (r10/r12/r15): +VALU work every time; loses.
//   - MERGE 2 states into one wave (r17): -TLP (1 wave/SIMD), ILP cannot
//     substitute on the in-order DS pipe; 65.7us. Loses.
//   => 1 state/wave, 2048 waves (2/SIMD) is the unique optimum topology.
// Other closed axes:
//   - (re,im) packing (r11): J-swizzle cost == pk gain; t-dim packing wins.
//   - b64/b128/paired LDS (r8/r10/r14): bank-structure losses; only t-major
//     b32 word(i)=(i&15)*64+(i>>4) is conflict-free (1.3e5 total).
// Residual: wall ~= VALU-issue 22.6us + DS ~20us, poorly overlapped at
// 2 waves/SIMD -- a latency plateau (VALU 46%, DS ~41%, neither saturated).
// Structure: one wave per state, 16 complex amps/lane, packed over t:
//   zr[k]=(re[t=k],re[t=k+8]), zi likewise -> element-wise v_pk_fma_f32
//   with wave-uniform scalar coeffs.
//  - wires 9..7 (t-bits 0..2): cross-pack register gates.
//  - wire 6 (t-bit 3 = pack dim): in-pack half-swap, packed constants.
//  - wires 5..2 (lane xor 1,2,4,8): DPP row ops (VALU pipe).
//  - wires 1,0 (lane xor 16,32): __shfl_xor.
//  - CNOT stage: composed GF(2)-linear permutation (g), one LDS round trip,
//    XOR-decomposed address tables in d_ws. No __syncthreads (single wave).

#define WIRES   10
#define NSTATE  1024
#define QDEPTH  8
#define NBATCH  2048
#define NGATES  (QDEPTH * WIRES)

typedef float v2f __attribute__((ext_vector_type(2)));
static __device__ __forceinline__ v2f s2(float x) { return (v2f){x, x}; }

// ws layout (floats/ints, 4 B each):
//   [0   .. 640)  gate coeffs gi=(l*10+q): u00r,u00i,u01r,u01i,u10r,u10i,u11r,u11i
//   [640 .. 768)  int gt[l*16+t]    = word(g_l(t))
//   [768 .. 1280) int glane[l*64+v] = word(g_l(v<<4))
#define WS_WORDS 1280

__device__ __forceinline__ int perm_g(int j, int r) {
#pragma unroll
    for (int q = WIRES - 1; q >= 0; --q) {
        const int cb = 9 - q;
        const int tb = 9 - ((q + r) % WIRES);
        j ^= ((j >> cb) & 1) << tb;
    }
    return j;
}

__global__ __launch_bounds__(1024) void qprep(
    const float* __restrict__ weights, float* __restrict__ ws)
{
    const int tid = threadIdx.x;
    if (tid < NGATES) {
        const float phi   = tanhf(weights[tid * 3 + 0]);
        const float theta = tanhf(weights[tid * 3 + 1]);
        const float omega = tanhf(weights[tid * 3 + 2]);
        const float c  = cosf(theta * 0.5f);
        const float sn = sinf(theta * 0.5f);
        const float a  = 0.5f * (phi + omega);
        const float bb = 0.5f * (phi - omega);
        const float ca = cosf(a),  sa = sinf(a);
        const float cb = cosf(bb), sb = sinf(bb);
        // U00 = e^{-ia} c ; U01 = -e^{+ib} s ; U10 = e^{-ib} s ; U11 = e^{+ia} c
        ws[tid * 8 + 0] =  ca * c;  ws[tid * 8 + 1] = -sa * c;
        ws[tid * 8 + 2] = -cb * sn; ws[tid * 8 + 3] = -sb * sn;
        ws[tid * 8 + 4] =  cb * sn; ws[tid * 8 + 5] = -sb * sn;
        ws[tid * 8 + 6] =  ca * c;  ws[tid * 8 + 7] =  sa * c;
    }
    int* wsI = (int*)ws;
    if (tid >= 128 && tid < 256) {          // gt table: 8 layers x 16 t
        const int e = tid - 128, l = e >> 4, t = e & 15;
        const int j = perm_g(t, (l % (WIRES - 1)) + 1);
        wsI[640 + e] = ((j & 15) << 6) | (j >> 4);
    }
    if (tid >= 256 && tid < 768) {          // glane table: 8 layers x 64 lanes
        const int e = tid - 256, l = e >> 6, v = e & 63;
        const int j = perm_g(v << 4, (l % (WIRES - 1)) + 1);
        wsI[768 + e] = ((j & 15) << 6) | (j >> 4);
    }
}

// DPP cross-lane move (VALU pipe, rows of 16 lanes) — validated r9/r13
template<int CTRL>
__device__ __forceinline__ float dppmov(float x) {
    return __int_as_float(__builtin_amdgcn_update_dpp(
        0, __float_as_int(x), CTRL, 0xF, 0xF, true));
}
#define FX1(v)  dppmov<0xB1>(v)
#define FX2(v)  dppmov<0x4E>(v)
#define FX4(v)  dppmov<0x1B>(dppmov<0x141>(v))
#define FX8(v)  dppmov<0x128>(v)
#define FX16(v) __shfl_xor((v), 16, 64)
#define FX32(v) __shfl_xor((v), 32, 64)

// local 2x2 gate along t-bit mask (1,2,4): partner in a DIFFERENT pack,
// matching halves -> pure packed element-wise math, scalar coeffs
#define APPLY_LOCAL_PK(uptr, mask)                                            \
    {                                                                         \
        const float* __restrict__ u = (uptr);                                 \
        const float u00r=u[0], u00i=u[1], u01r=u[2], u01i=u[3];               \
        const float u10r=u[4], u10i=u[5], u11r=u[6], u11i=u[7];               \
        _Pragma("unroll")                                                     \
        for (int k0 = 0; k0 < 8; ++k0) {                                      \
            if (k0 & (mask)) continue;                                        \
            const int k1 = k0 | (mask);                                       \
            const v2f a0r = zr[k0], a0i = zi[k0];                             \
            const v2f a1r = zr[k1], a1i = zi[k1];                             \
            zr[k0] = s2(u00r)*a0r - s2(u00i)*a0i + s2(u01r)*a1r - s2(u01i)*a1i;\
            zi[k0] = s2(u00r)*a0i + s2(u00i)*a0r + s2(u01r)*a1i + s2(u01i)*a1r;\
            zr[k1] = s2(u10r)*a0r - s2(u10i)*a0i + s2(u11r)*a1r - s2(u11i)*a1i;\
            zi[k1] = s2(u10r)*a0i + s2(u10i)*a0r + s2(u11r)*a1i + s2(u11i)*a1r;\
        }                                                                     \
    }

// gate on lane-bit J (wire W): partner via per-half FETCH, scalar coeffs
#define LANE_GATE_PK(W, J, FETCH)                                             \
    {                                                                         \
        const float* __restrict__ u = gw + (W) * 8;                           \
        const bool hi = (lane >> (J)) & 1;                                    \
        const float c0r = hi ? u[6] : u[0], c0i = hi ? u[7] : u[1];           \
        const float c1r = hi ? u[4] : u[2], c1i = hi ? u[5] : u[3];           \
        _Pragma("unroll")                                                     \
        for (int k = 0; k < 8; ++k) {                                         \
            v2f pr, pi;                                                       \
            pr.x = FETCH(zr[k].x); pr.y = FETCH(zr[k].y);                     \
            pi.x = FETCH(zi[k].x); pi.y = FETCH(zi[k].y);                     \
            const v2f sr = zr[k], si = zi[k];                                 \
            zr[k] = s2(c0r)*sr - s2(c0i)*si + s2(c1r)*pr - s2(c1i)*pi;        \
            zi[k] = s2(c0r)*si + s2(c0i)*sr + s2(c1r)*pi + s2(c1i)*pr;        \
        }                                                                     \
    }

__global__ __launch_bounds__(64) void qsim_wave(
    const float* __restrict__ x,
    const float* __restrict__ ws,
    float* __restrict__ out,
    const int interleaved)
{
    __shared__ float lre[NSTATE];
    __shared__ float lim[NSTATE];
    const int lane = threadIdx.x;           // 0..63
    const int b    = blockIdx.x;
    const int* __restrict__ wsI = (const int*)ws;

    // packed planes: zr[k] = (re[t=k], re[t=k+8]); zi likewise
    v2f zr[8], zi[8];

    // ---- load 16 contiguous amplitudes (real input, imag = 0) ----
    const float4* __restrict__ x4 =
        (const float4*)(x + ((size_t)b << 10) + (lane << 4));
    {
        const float4 v0 = x4[0], v1 = x4[1], v2 = x4[2], v3 = x4[3];
        zr[0].x=v0.x; zr[1].x=v0.y; zr[2].x=v0.z; zr[3].x=v0.w;
        zr[4].x=v1.x; zr[5].x=v1.y; zr[6].x=v1.z; zr[7].x=v1.w;
        zr[0].y=v2.x; zr[1].y=v2.y; zr[2].y=v2.z; zr[3].y=v2.w;
        zr[4].y=v3.x; zr[5].y=v3.y; zr[6].y=v3.z; zr[7].y=v3.w;
#pragma unroll
        for (int k = 0; k < 8; ++k) zi[k] = (v2f){0.f, 0.f};
    }

    for (int l = 0; l < QDEPTH; ++l) {
        const float* __restrict__ gw = ws + l * 80;

        // ---- local gates: t-bits 0,1,2 = wires 9,8,7 (cross-pack) ----
        APPLY_LOCAL_PK(gw + 9*8, 1)
        APPLY_LOCAL_PK(gw + 8*8, 2)
        APPLY_LOCAL_PK(gw + 7*8, 4)

        // ---- t-bit 3 = wire 6: lo<->hi within each pack (half-swap) ----
        {
            const float* __restrict__ u = gw + 6*8;
            const v2f pAr = (v2f){u[0], u[6]};   // (u00r, u11r)
            const v2f pAi = (v2f){u[1], u[7]};   // (u00i, u11i)
            const v2f pBr = (v2f){u[2], u[4]};   // (u01r, u10r)
            const v2f pBi = (v2f){u[3], u[5]};   // (u01i, u10i)
#pragma unroll
            for (int k = 0; k < 8; ++k) {
                const v2f r  = zr[k], i = zi[k];
                const v2f rs = __builtin_shufflevector(r, r, 1, 0);
                const v2f is = __builtin_shufflevector(i, i, 1, 0);
                zr[k] = pAr*r - pAi*i + pBr*rs - pBi*is;
                zi[k] = pAr*i + pAi*r + pBr*is + pBi*rs;
            }
        }

        // ---- lane-bit gates: wires 5..2 on DPP, wires 1,0 via shfl ----
        LANE_GATE_PK(5, 0, FX1)
        LANE_GATE_PK(4, 1, FX2)
        LANE_GATE_PK(3, 2, FX4)
        LANE_GATE_PK(2, 3, FX8)
        LANE_GATE_PK(1, 4, FX16)
        LANE_GATE_PK(0, 5, FX32)

        // ---- CNOT stage: new[i] = old[g(i)] via one LDS round trip ----
        // t-major b32 SoA, word(i) = t*64 + lane (bank = lane mod 32: free)
#pragma unroll
        for (int k = 0; k < 8; ++k) {
            lre[k * 64 + lane]         = zr[k].x;
            lre[(k + 8) * 64 + lane]   = zr[k].y;
            lim[k * 64 + lane]         = zi[k].x;
            lim[(k + 8) * 64 + lane]   = zi[k].y;
        }
        // single wave: per-wave DS ops execute in order; no barrier needed
        const int ga = wsI[768 + l * 64 + lane];    // word(g(lane<<4))
#pragma unroll
        for (int k = 0; k < 8; ++k) {
            const int a0 = ga ^ wsI[640 + l * 16 + k];
            const int a1 = ga ^ wsI[640 + l * 16 + k + 8];
            zr[k].x = lre[a0]; zi[k].x = lim[a0];
            zr[k].y = lre[a1]; zi[k].y = lim[a1];
        }
    }

    // ---- epilogue ----
    if (interleaved) {
        float2* __restrict__ o2 = (float2*)out;
        const size_t base = ((size_t)b << 10) + (lane << 4);
#pragma unroll
        for (int k = 0; k < 8; ++k) {
            o2[base + k]     = make_float2(zr[k].x, zi[k].x);
            o2[base + k + 8] = make_float2(zr[k].y, zi[k].y);
        }
    } else {
        // harness compares real part only (complex64 expected cast to float32)
        float4* __restrict__ o4 = (float4*)(out + ((size_t)b << 10) + (lane << 4));
        o4[0] = make_float4(zr[0].x, zr[1].x, zr[2].x, zr[3].x);
        o4[1] = make_float4(zr[4].x, zr[5].x, zr[6].x, zr[7].x);
        o4[2] = make_float4(zr[0].y, zr[1].y, zr[2].y, zr[3].y);
        o4[3] = make_float4(zr[4].y, zr[5].y, zr[6].y, zr[7].y);
    }
}

// ---------------- validated round-6 fallback (ws too small) ----------------
__global__ __launch_bounds__(256) void qcircuit_kernel(
    const float* __restrict__ x, const float* __restrict__ weights,
    float* __restrict__ out, const int interleaved)
{
    __shared__ float s_re[NSTATE];
    __shared__ float s_im[NSTATE];
    __shared__ float s_g[NGATES][8];
    const int tid = threadIdx.x;
    const int b   = blockIdx.x;
    if (tid < NGATES) {
        const float phi   = tanhf(weights[tid * 3 + 0]);
        const float theta = tanhf(weights[tid * 3 + 1]);
        const float omega = tanhf(weights[tid * 3 + 2]);
        const float c  = cosf(theta * 0.5f);
        const float sn = sinf(theta * 0.5f);
        const float a  = 0.5f * (phi + omega);
        const float bb = 0.5f * (phi - omega);
        const float ca = cosf(a),  sa = sinf(a);
        const float cb = cosf(bb), sb = sinf(bb);
        s_g[tid][0] =  ca * c;  s_g[tid][1] = -sa * c;
        s_g[tid][2] = -cb * sn; s_g[tid][3] = -sb * sn;
        s_g[tid][4] =  cb * sn; s_g[tid][5] = -sb * sn;
        s_g[tid][6] =  ca * c;  s_g[tid][7] =  sa * c;
    }
#pragma unroll
    for (int k = 0; k < 4; ++k) {
        const int i = tid + 256 * k;
        s_re[i] = x[b * NSTATE + i];
        s_im[i] = 0.0f;
    }
    __syncthreads();
    for (int l = 0; l < QDEPTH; ++l) {
        for (int q = 0; q < WIRES; ++q) {
            const int gi = l * WIRES + q;
            const float u00r = s_g[gi][0], u00i = s_g[gi][1];
            const float u01r = s_g[gi][2], u01i = s_g[gi][3];
            const float u10r = s_g[gi][4], u10i = s_g[gi][5];
            const float u11r = s_g[gi][6], u11i = s_g[gi][7];
            const int sh = 9 - q;
            const int m  = 1 << sh;
#pragma unroll
            for (int k = 0; k < 2; ++k) {
                const int p  = tid + 256 * k;
                const int i0 = ((p >> sh) << (sh + 1)) | (p & (m - 1));
                const int i1 = i0 | m;
                const float a0r = s_re[i0], a0i = s_im[i0];
                const float a1r = s_re[i1], a1i = s_im[i1];
                s_re[i0] = u00r*a0r - u00i*a0i + u01r*a1r - u01i*a1i;
                s_im[i0] = u00r*a0i + u00i*a0r + u01r*a1i + u01i*a1r;
                s_re[i1] = u10r*a0r - u10i*a0i + u11r*a1r - u11i*a1i;
                s_im[i1] = u10r*a0i + u10i*a0r + u11r*a1i + u11i*a1r;
            }
            __syncthreads();
        }
        const int r = (l % (WIRES - 1)) + 1;
        float vr[4], vi[4];
#pragma unroll
        for (int k = 0; k < 4; ++k) {
            const int i = tid + 256 * k;
            const int j = perm_g(i, r);
            vr[k] = s_re[j]; vi[k] = s_im[j];
        }
        __syncthreads();
#pragma unroll
        for (int k = 0; k < 4; ++k) {
            const int i = tid + 256 * k;
            s_re[i] = vr[k]; s_im[i] = vi[k];
        }
        __syncthreads();
    }
    if (interleaved) {
#pragma unroll
        for (int k = 0; k < 4; ++k) {
            const int i  = tid + 256 * k;
            const int fi = 2 * (b * NSTATE + i);
            out[fi + 0] = s_re[i];
            out[fi + 1] = s_im[i];
        }
    } else {
#pragma unroll
        for (int k = 0; k < 4; ++k) {
            const int i = tid + 256 * k;
            out[b * NSTATE + i] = s_re[i];
        }
    }
}

extern "C" void kernel_launch(void* const* d_in, const int* in_sizes, int n_in,
                              void* d_out, int out_size, void* d_ws, size_t ws_size,
                              hipStream_t stream) {
    const float* x       = (const float*)d_in[0];   // (2048,1,32,32) f32
    const float* weights = (const float*)d_in[1];   // (8,10,3) f32
    float* out = (float*)d_out;
    const int interleaved = (out_size >= 2 * NBATCH * NSTATE) ? 1 : 0;

    if (ws_size >= WS_WORDS * sizeof(float)) {
        float* ws = (float*)d_ws;
        qprep<<<1, 1024, 0, stream>>>(weights, ws);
        qsim_wave<<<NBATCH, 64, 0, stream>>>(x, ws, out, interleaved);
    } else {
        qcircuit_kernel<<<NBATCH, 256, 0, stream>>>(x, weights, out, interleaved);
    }
}